// Round 16
// baseline (269.367 us; speedup 1.0000x reference)
//
#include <hip/hip_runtime.h>
#include <math.h>

#define NT 100000
#define ET 1600000
#define GT 128
#define NBK 391      // dst>>8 buckets (256 nodes each)
#define BSH 8
#define NBLK_A 256   // blocks in hist/bucketize passes
#define CHUNK_A 6250 // ET / NBLK_A

typedef float f4 __attribute__((ext_vector_type(4)));

__device__ __forceinline__ float lrelu(float v) { return v > 0.0f ? v : 0.2f * v; }
__device__ __forceinline__ float elu1(float v) { return v > 0.0f ? v : __expf(v) - 1.0f; }

// ---------------- CSR build: bucketed two-level, no global atomics ----------------
__global__ __launch_bounds__(256) void k_histA(const int* __restrict__ dst, int* __restrict__ histA) {
  __shared__ int histL[NBK];
  int t = threadIdx.x, blk = blockIdx.x;
  for (int i = t; i < NBK; i += 256) histL[i] = 0;
  __syncthreads();
  int e0 = blk * CHUNK_A, e1 = min(ET, e0 + CHUNK_A);
  for (int e = e0 + t; e < e1; e += 256) atomicAdd(&histL[dst[e] >> BSH], 1);
  __syncthreads();
  for (int i = t; i < NBK; i += 256) histA[i * NBLK_A + blk] = histL[i];
}

__global__ __launch_bounds__(256) void k_scanB(int* __restrict__ histA, int* __restrict__ btot) {
  __shared__ int sh[256];
  int b = blockIdx.x, t = threadIdx.x;
  int v = histA[b * NBLK_A + t];
  sh[t] = v;
  __syncthreads();
  for (int off = 1; off < 256; off <<= 1) {
    int xv = (t >= off) ? sh[t - off] : 0;
    __syncthreads();
    sh[t] += xv;
    __syncthreads();
  }
  histA[b * NBLK_A + t] = sh[t] - v;
  if (t == 255) btot[b] = sh[255];
}

__global__ __launch_bounds__(512) void k_scanC(const int* __restrict__ btot, int* __restrict__ bbase) {
  __shared__ int sh[512];
  int t = threadIdx.x;
  int v = (t < NBK) ? btot[t] : 0;
  sh[t] = v;
  __syncthreads();
  for (int off = 1; off < 512; off <<= 1) {
    int xv = (t >= off) ? sh[t - off] : 0;
    __syncthreads();
    sh[t] += xv;
    __syncthreads();
  }
  if (t < NBK) bbase[t] = sh[t] - v;
  if (t == 0) bbase[NBK] = ET;
}

// bucketize edges into packed ebuf: (dst&255)<<17 | src   (src < 2^17)
__global__ __launch_bounds__(256) void k_buck(const int* __restrict__ src, const int* __restrict__ dst,
                                              const int* __restrict__ histA, const int* __restrict__ bbase,
                                              unsigned int* __restrict__ ebuf) {
  __shared__ int cur[NBK];
  int t = threadIdx.x, blk = blockIdx.x;
  for (int i = t; i < NBK; i += 256) cur[i] = histA[i * NBLK_A + blk] + bbase[i];
  __syncthreads();
  int e0 = blk * CHUNK_A, e1 = min(ET, e0 + CHUNK_A);
  for (int e = e0 + t; e < e1; e += 256) {
    unsigned int s = (unsigned int)src[e];
    int d = dst[e];
    int pos = atomicAdd(&cur[d >> BSH], 1);
    ebuf[pos] = ((unsigned int)(d & 255) << 17) | s;
  }
}

__global__ __launch_bounds__(256) void k_fine(const unsigned int* __restrict__ ebuf, const int* __restrict__ bbase,
                                              int* __restrict__ rp, int* __restrict__ adj) {
  __shared__ int cnt[256];
  __shared__ int sh[256];
  __shared__ int cur[256];
  int b = blockIdx.x, t = threadIdx.x;
  int eb0 = bbase[b], eb1 = bbase[b + 1];
  cnt[t] = 0;
  __syncthreads();
  for (int e = eb0 + t; e < eb1; e += 256) atomicAdd(&cnt[ebuf[e] >> 17], 1);
  __syncthreads();
  int v = cnt[t];
  sh[t] = v;
  __syncthreads();
  for (int off = 1; off < 256; off <<= 1) {
    int xv = (t >= off) ? sh[t - off] : 0;
    __syncthreads();
    sh[t] += xv;
    __syncthreads();
  }
  int start = eb0 + sh[t] - v;
  cur[t] = start;
  int node = (b << BSH) + t;
  if (node < NT) rp[node] = start;
  if (node == NT - 1) rp[NT] = ET;
  __syncthreads();
  for (int e = eb0 + t; e < eb1; e += 256) {
    unsigned int p = ebuf[e];
    int pos = atomicAdd(&cur[p >> 17], 1);
    adj[pos] = (int)(p & 0x1FFFFu);
  }
}

// ---------------- prep: AB[k][j] = sum_c W1[k][h*32+c] * a[h][c]  (j<4: src, j>=4: dst) ----------------
__global__ void k_prep(const float* __restrict__ W1, const float* __restrict__ as1,
                       const float* __restrict__ ad1, float* __restrict__ AB) {
  int t = threadIdx.x;  // 256
  int k = t >> 3, j = t & 7;
  const float* a = (j < 4) ? as1 : ad1;
  int h = j & 3;
  float s = 0.0f;
  for (int c = 0; c < 32; ++c) s += W1[k * 128 + h * 32 + c] * a[h * 32 + c];
  AB[t] = s;  // AB[k*8 + j]
}

// ---------------- att1: es1/ed1 = x @ AB (N x 32 x 8) ----------------
__global__ __launch_bounds__(256) void k_att1(const float* __restrict__ x, const float* __restrict__ AB,
                                              float* __restrict__ es, float* __restrict__ ed) {
  __shared__ float xsh[32 * 33];
  __shared__ float absh[256];
  int t = threadIdx.x;
  int n0 = blockIdx.x * 32;
  absh[t] = AB[t];
  for (int i = t; i < 1024; i += 256) {
    int ln = i >> 5, k = i & 31;
    int node = n0 + ln;
    xsh[ln * 33 + k] = (node < NT) ? x[node * 32 + k] : 0.0f;
  }
  __syncthreads();
  int ln = t >> 3, j = t & 7;
  int node = n0 + ln;
  if (node < NT) {
    float s = 0.0f;
#pragma unroll
    for (int k = 0; k < 32; ++k) s += xsh[ln * 33 + k] * absh[k * 8 + j];
    if (j < 4) es[node * 4 + j] = s;
    else ed[node * 4 + (j - 4)] = s;
  }
}

// ---------------- agg1f: fused L1 aggregate + L1 matvec + ELU + L2 GEMM + L2 logits ----------------
// r10 structure (8 nodes/block, gather 2 nodes/wave, matvecs block-wide from global W).
// NEW: all gather/stream loads nontemporal so W1/W2 (32KB) stay L1-resident.
__global__ __launch_bounds__(256) void k_agg1f(
    const int* __restrict__ rp, const int* __restrict__ adj,
    const float* __restrict__ es, const float* __restrict__ ed,
    const float* __restrict__ x,
    const float* __restrict__ W1, const float* __restrict__ b1,
    const float* __restrict__ W2,
    const float* __restrict__ as2, const float* __restrict__ ad2,
    float* __restrict__ h2, float* __restrict__ es2, float* __restrict__ ed2) {
  __shared__ int sbuf[8][34];
  __shared__ f4 wbufv[8][34];
  __shared__ float ysh[8][132];   // [ns][h*33+k]
  __shared__ float osh[8][132];   // [ns][kg*33+kk]
  int t = threadIdx.x;
  int wv = t >> 6, l = t & 63;
  int g = l >> 5, j = l & 31;
  int ns = wv * 2 + g;
  int n = blockIdx.x * 8 + ns;
  bool valid = (n < NT);
  int nc = valid ? n : NT - 1;
  const f4* es4 = (const f4*)es;
  int rs = rp[nc], re = rp[nc + 1];
  int deg = re - rs;
  f4 edn = ((const f4*)ed)[nc];
  f4 esn = es4[nc];
  float sv[4];
#pragma unroll
  for (int h = 0; h < 4; ++h) sv[h] = __expf(lrelu(esn[h] + edn[h]));
  int eg2 = j >> 3, q = j & 7;
  f4 a0 = {0,0,0,0}, a1 = {0,0,0,0}, a2 = {0,0,0,0}, a3 = {0,0,0,0};

  if (deg <= 32) {
    float ex[4] = {0.0f, 0.0f, 0.0f, 0.0f};
    if (j < deg) {
      int s = __builtin_nontemporal_load(&adj[rs + j]);
      sbuf[ns][j] = s;
      f4 ev = __builtin_nontemporal_load(&es4[s]);
#pragma unroll
      for (int h = 0; h < 4; ++h) ex[h] = __expf(lrelu(ev[h] + edn[h]));
    }
    float d[4] = {ex[0], ex[1], ex[2], ex[3]};
#pragma unroll
    for (int off = 1; off <= 16; off <<= 1)
#pragma unroll
      for (int h = 0; h < 4; ++h) d[h] += __shfl_xor(d[h], off);
    float inv[4];
#pragma unroll
    for (int h = 0; h < 4; ++h) inv[h] = 1.0f / (d[h] + sv[h]);
    if (j < deg) {
      f4 w4;
#pragma unroll
      for (int h = 0; h < 4; ++h) w4[h] = ex[h] * inv[h];
      wbufv[ns][j] = w4;
    }
    if (j == 0) {
      sbuf[ns][deg] = nc;
      f4 w4;
#pragma unroll
      for (int h = 0; h < 4; ++h) w4[h] = sv[h] * inv[h];
      wbufv[ns][deg] = w4;
    }
    __builtin_amdgcn_wave_barrier();
    for (int e = eg2; e <= deg; e += 4) {
      f4 xv = __builtin_nontemporal_load((const f4*)&x[sbuf[ns][e] * 32 + 4 * q]);
      f4 w4 = wbufv[ns][e];
      a0 += w4.x * xv; a1 += w4.y * xv; a2 += w4.z * xv; a3 += w4.w * xv;
    }
  } else {
    // generic (deg > 32, rare): no-max two-pass chunked
    float d[4] = {0.0f, 0.0f, 0.0f, 0.0f};
    for (int jj = rs + j; jj < re; jj += 32) {
      int s = __builtin_nontemporal_load(&adj[jj]);
      f4 ev = __builtin_nontemporal_load(&es4[s]);
#pragma unroll
      for (int h = 0; h < 4; ++h) d[h] += __expf(lrelu(ev[h] + edn[h]));
    }
#pragma unroll
    for (int off = 1; off <= 16; off <<= 1)
#pragma unroll
      for (int h = 0; h < 4; ++h) d[h] += __shfl_xor(d[h], off);
    float inv[4];
#pragma unroll
    for (int h = 0; h < 4; ++h) inv[h] = 1.0f / (d[h] + sv[h]);
    for (int base = rs; base < re; base += 32) {
      int cnt = min(32, re - base);
      if (j < cnt) {
        int s = __builtin_nontemporal_load(&adj[base + j]);
        sbuf[ns][j] = s;
        f4 ev = __builtin_nontemporal_load(&es4[s]);
        f4 w4;
#pragma unroll
        for (int h = 0; h < 4; ++h) w4[h] = __expf(lrelu(ev[h] + edn[h])) * inv[h];
        wbufv[ns][j] = w4;
      }
      __builtin_amdgcn_wave_barrier();
      for (int e = eg2; e < cnt; e += 4) {
        f4 xv = __builtin_nontemporal_load((const f4*)&x[sbuf[ns][e] * 32 + 4 * q]);
        f4 w4 = wbufv[ns][e];
        a0 += w4.x * xv; a1 += w4.y * xv; a2 += w4.z * xv; a3 += w4.w * xv;
      }
      __builtin_amdgcn_wave_barrier();
    }
    if (eg2 == 0) {
      f4 xv = __builtin_nontemporal_load((const f4*)&x[nc * 32 + 4 * q]);
      a0 += sv[0] * inv[0] * xv; a1 += sv[1] * inv[1] * xv;
      a2 += sv[2] * inv[2] * xv; a3 += sv[3] * inv[3] * xv;
    }
  }

  // reduce across 4 edge-groups (xor 8, 16 stay within each 32-half)
#pragma unroll
  for (int off = 8; off <= 16; off <<= 1) {
#pragma unroll
    for (int cc = 0; cc < 4; ++cc) {
      a0[cc] += __shfl_xor(a0[cc], off);
      a1[cc] += __shfl_xor(a1[cc], off);
      a2[cc] += __shfl_xor(a2[cc], off);
      a3[cc] += __shfl_xor(a3[cc], off);
    }
  }
  if (eg2 == 0) {
    *(f4*)&ysh[ns][0 * 33 + 4 * q] = a0;
    *(f4*)&ysh[ns][1 * 33 + 4 * q] = a1;
    *(f4*)&ysh[ns][2 * 33 + 4 * q] = a2;
    *(f4*)&ysh[ns][3 * 33 + 4 * q] = a3;
  }
  __syncthreads();

  // matvec1 + ELU, block-wide: thread t -> node ns2=t>>5, channels ch..ch+3 (W1 from L1)
  {
    int ns2 = t >> 5, j2 = t & 31;
    int ch = j2 * 4, hh = j2 >> 3;
    f4 o = {0,0,0,0};
#pragma unroll
    for (int k = 0; k < 32; ++k) {
      o += ysh[ns2][hh * 33 + k] * *(const f4*)&W1[k * 128 + ch];
    }
    o += *(const f4*)&b1[ch];
#pragma unroll
    for (int cc = 0; cc < 4; ++cc) o[cc] = elu1(o[cc]);
    *(f4*)&osh[ns2][(ch >> 5) * 33 + (ch & 31)] = o;
  }
  __syncthreads();

  // matvec2, block-wide: thread t -> node ns2, k-group kg, channels c4..c4+3 (W2 from L1)
  {
    int ns2 = t >> 5, j2 = t & 31;
    int kg = j2 >> 3, c4 = (j2 & 7) * 4;
    int n2 = blockIdx.x * 8 + ns2;
    bool v2 = (n2 < NT);
    f4 p = {0,0,0,0};
#pragma unroll
    for (int kk = 0; kk < 32; ++kk) {
      p += osh[ns2][kg * 33 + kk] * *(const f4*)&W2[(kg * 32 + kk) * 32 + c4];
    }
#pragma unroll
    for (int off = 8; off <= 16; off <<= 1)
#pragma unroll
      for (int cc = 0; cc < 4; ++cc) p[cc] += __shfl_xor(p[cc], off);
    if (kg == 0) {
      if (v2) *(f4*)&h2[n2 * 32 + c4] = p;
      f4 av = *(const f4*)&as2[c4];
      f4 dv = *(const f4*)&ad2[c4];
      float ps = p.x * av.x + p.y * av.y + p.z * av.z + p.w * av.w;
      float pd = p.x * dv.x + p.y * dv.y + p.z * dv.z + p.w * dv.w;
#pragma unroll
      for (int off = 1; off <= 4; off <<= 1) {
        ps += __shfl_xor(ps, off);
        pd += __shfl_xor(pd, off);
      }
      if ((j2 & 7) == 0 && v2) { es2[n2] = ps; ed2[n2] = pd; }
    }
  }
}

// ---------------- agg2: 2 nodes/wave, no-max softmax, fused h2o.Wc -> z ----------------
__global__ __launch_bounds__(256) void k_agg2(const int* __restrict__ rp, const int* __restrict__ adj,
                                              const float* __restrict__ es, const float* __restrict__ ed,
                                              const float* __restrict__ h, const float* __restrict__ b2,
                                              const float* __restrict__ Wc, float* __restrict__ z) {
  __shared__ int sbuf[8][34];
  __shared__ float wsh[8][34];
  int t = threadIdx.x;
  int wv = t >> 6, l = t & 63;
  int g = l >> 5, j = l & 31;
  int ns = wv * 2 + g;
  int n = blockIdx.x * 8 + ns;
  if (n >= NT) return;
  int rs = rp[n], re = rp[n + 1];
  int deg = re - rs;
  float edn = ed[n];
  float sv = __expf(lrelu(es[n] + edn));
  int eg2 = j >> 3, q = j & 7;
  f4 acc = {0,0,0,0};

  if (deg <= 32) {
    float ex = 0.0f;
    if (j < deg) {
      int s = __builtin_nontemporal_load(&adj[rs + j]);
      sbuf[ns][j] = s;
      ex = __expf(lrelu(__builtin_nontemporal_load(&es[s]) + edn));
    }
    float d = ex;
#pragma unroll
    for (int off = 1; off <= 16; off <<= 1) d += __shfl_xor(d, off);
    float inv = 1.0f / (d + sv);
    if (j < deg) wsh[ns][j] = ex * inv;
    if (j == 0) { sbuf[ns][deg] = n; wsh[ns][deg] = sv * inv; }
    __builtin_amdgcn_wave_barrier();
    for (int e = eg2; e <= deg; e += 4) {
      f4 hv = __builtin_nontemporal_load((const f4*)&h[sbuf[ns][e] * 32 + 4 * q]);
      acc += wsh[ns][e] * hv;
    }
  } else {
    float d = 0.0f;
    for (int jj = rs + j; jj < re; jj += 32) {
      int s = __builtin_nontemporal_load(&adj[jj]);
      d += __expf(lrelu(__builtin_nontemporal_load(&es[s]) + edn));
    }
#pragma unroll
    for (int off = 1; off <= 16; off <<= 1) d += __shfl_xor(d, off);
    float inv = 1.0f / (d + sv);
    for (int base = rs; base < re; base += 32) {
      int cnt = min(32, re - base);
      if (j < cnt) {
        int s = __builtin_nontemporal_load(&adj[base + j]);
        sbuf[ns][j] = s;
        wsh[ns][j] = __expf(lrelu(__builtin_nontemporal_load(&es[s]) + edn)) * inv;
      }
      __builtin_amdgcn_wave_barrier();
      for (int e = eg2; e < cnt; e += 4) {
        f4 hv = __builtin_nontemporal_load((const f4*)&h[sbuf[ns][e] * 32 + 4 * q]);
        acc += wsh[ns][e] * hv;
      }
      __builtin_amdgcn_wave_barrier();
    }
    if (eg2 == 0) acc += sv * inv * *(const f4*)&h[n * 32 + 4 * q];
  }

#pragma unroll
  for (int off = 8; off <= 16; off <<= 1)
#pragma unroll
    for (int cc = 0; cc < 4; ++cc) acc[cc] += __shfl_xor(acc[cc], off);
  if (eg2 == 0) {
    f4 o = acc + *(const f4*)&b2[4 * q];
#pragma unroll
    for (int cc = 0; cc < 4; ++cc) o[cc] = elu1(o[cc]);
    f4 wc = *(const f4*)&Wc[4 * q];
    float zz = o.x * wc.x + o.y * wc.y + o.z * wc.z + o.w * wc.w;
#pragma unroll
    for (int off = 1; off <= 4; off <<= 1) zz += __shfl_xor(zz, off);
    if (q == 0) z[n] = zz;
  }
}

// ---------------- pooling: one block per graph, sums scalar z ----------------
__global__ __launch_bounds__(256) void k_poolz(const float* __restrict__ z, const int* __restrict__ batch,
                                               const float* __restrict__ bc, float* __restrict__ out) {
  int g = blockIdx.x;
  int lo = 0, hi = NT;
  while (lo < hi) { int mid = (lo + hi) >> 1; if (batch[mid] < g) lo = mid + 1; else hi = mid; }
  int start = lo;
  hi = NT;
  while (lo < hi) { int mid = (lo + hi) >> 1; if (batch[mid] < g + 1) lo = mid + 1; else hi = mid; }
  int end = lo;

  int t = threadIdx.x;
  float s = 0.0f;
  for (int n = start + t; n < end; n += 256) s += z[n];
#pragma unroll
  for (int off = 1; off <= 32; off <<= 1) s += __shfl_xor(s, off);
  __shared__ float sh[4];
  if ((t & 63) == 0) sh[t >> 6] = s;
  __syncthreads();
  if (t == 0) {
    float tot = sh[0] + sh[1] + sh[2] + sh[3];
    float cnt = (float)(end - start);
    out[g] = tot / fmaxf(cnt, 1.0f) + bc[0];
  }
}

extern "C" void kernel_launch(void* const* d_in, const int* in_sizes, int n_in,
                              void* d_out, int out_size, void* d_ws, size_t ws_size,
                              hipStream_t stream) {
  const float* x = (const float*)d_in[0];
  const int* ei = (const int*)d_in[1];
  const int* src = ei;
  const int* dst = ei + ET;
  const int* batch = (const int*)d_in[2];
  const float* W1 = (const float*)d_in[3];
  const float* asrc1 = (const float*)d_in[4];
  const float* adst1 = (const float*)d_in[5];
  const float* b1 = (const float*)d_in[6];
  const float* W2 = (const float*)d_in[7];
  const float* asrc2 = (const float*)d_in[8];
  const float* adst2 = (const float*)d_in[9];
  const float* b2 = (const float*)d_in[10];
  const float* Wc = (const float*)d_in[11];
  const float* bc = (const float*)d_in[12];
  float* out = (float*)d_out;
  char* ws = (char*)d_ws;

  int* row_ptr = (int*)(ws + 0);              // -> 400128
  int* histA = (int*)(ws + 400128);           // -> 800512
  int* btot = (int*)(ws + 800512);            // -> 802112
  int* bbase = (int*)(ws + 802112);           // -> 803712
  float* AB = (float*)(ws + 803712);          // -> 804736
  unsigned int* ebuf = (unsigned int*)(ws + 804736);  // 6.4MB -> 7204736
  int* adj = (int*)(ws + 7204736);            // 6.4MB -> 13604736
  float* es1 = (float*)(ws + 13604736);       // 1.6MB
  float* ed1 = (float*)(ws + 15204736);       // 1.6MB
  float* es2 = (float*)(ws + 16804736);       // 400KB
  float* ed2 = (float*)(ws + 17204736);       // 400KB
  float* h2 = (float*)(ws + 17604736);        // 12.8MB -> 30404736
  float* z = (float*)(ws + 30404736);         // 400KB

  // CSR build (bucketed, no global atomics)
  k_histA<<<NBLK_A, 256, 0, stream>>>(dst, histA);
  k_scanB<<<NBK, 256, 0, stream>>>(histA, btot);
  k_scanC<<<1, 512, 0, stream>>>(btot, bbase);
  k_buck<<<NBLK_A, 256, 0, stream>>>(src, dst, histA, bbase, ebuf);
  k_fine<<<NBK, 256, 0, stream>>>(ebuf, bbase, row_ptr, adj);

  // layer 1 attention logits
  k_prep<<<1, 256, 0, stream>>>(W1, asrc1, adst1, AB);
  k_att1<<<(NT + 31) / 32, 256, 0, stream>>>(x, AB, es1, ed1);

  // fused: L1 aggregate (input space) + L1 matvec + ELU + L2 GEMM + L2 logits
  k_agg1f<<<(NT + 7) / 8, 256, 0, stream>>>(row_ptr, adj, es1, ed1, x, W1, b1, W2,
                                            asrc2, adst2, h2, es2, ed2);

  // layer 2 aggregation + ELU + classifier dot
  k_agg2<<<(NT + 7) / 8, 256, 0, stream>>>(row_ptr, adj, es2, ed2, h2, b2, Wc, z);

  // pool + bias
  k_poolz<<<GT, 256, 0, stream>>>(z, batch, bc, out);
}

// Round 17
// 222.024 us; speedup vs baseline: 1.2132x; 1.2132x over previous
//
#include <hip/hip_runtime.h>
#include <math.h>

#define NT 100000
#define ET 1600000
#define GT 128
#define NBK 391      // dst>>8 buckets (256 nodes each)
#define BSH 8
#define NBLK_A 256   // blocks in hist/bucketize passes
#define CHUNK_A 6250 // ET / NBLK_A

typedef float f4 __attribute__((ext_vector_type(4)));

__device__ __forceinline__ float lrelu(float v) { return v > 0.0f ? v : 0.2f * v; }
__device__ __forceinline__ float elu1(float v) { return v > 0.0f ? v : __expf(v) - 1.0f; }

// ---------------- CSR build: bucketed two-level, no global atomics ----------------
__global__ __launch_bounds__(256) void k_histA(const int* __restrict__ dst, int* __restrict__ histA) {
  __shared__ int histL[NBK];
  int t = threadIdx.x, blk = blockIdx.x;
  for (int i = t; i < NBK; i += 256) histL[i] = 0;
  __syncthreads();
  int e0 = blk * CHUNK_A, e1 = min(ET, e0 + CHUNK_A);
  for (int e = e0 + t; e < e1; e += 256) atomicAdd(&histL[dst[e] >> BSH], 1);
  __syncthreads();
  for (int i = t; i < NBK; i += 256) histA[i * NBLK_A + blk] = histL[i];
}

__global__ __launch_bounds__(256) void k_scanB(int* __restrict__ histA, int* __restrict__ btot) {
  __shared__ int sh[256];
  int b = blockIdx.x, t = threadIdx.x;
  int v = histA[b * NBLK_A + t];
  sh[t] = v;
  __syncthreads();
  for (int off = 1; off < 256; off <<= 1) {
    int xv = (t >= off) ? sh[t - off] : 0;
    __syncthreads();
    sh[t] += xv;
    __syncthreads();
  }
  histA[b * NBLK_A + t] = sh[t] - v;
  if (t == 255) btot[b] = sh[255];
}

__global__ __launch_bounds__(512) void k_scanC(const int* __restrict__ btot, int* __restrict__ bbase) {
  __shared__ int sh[512];
  int t = threadIdx.x;
  int v = (t < NBK) ? btot[t] : 0;
  sh[t] = v;
  __syncthreads();
  for (int off = 1; off < 512; off <<= 1) {
    int xv = (t >= off) ? sh[t - off] : 0;
    __syncthreads();
    sh[t] += xv;
    __syncthreads();
  }
  if (t < NBK) bbase[t] = sh[t] - v;
  if (t == 0) bbase[NBK] = ET;
}

// bucketize edges into ebuf (LDS cursors; writes cluster per bucket region)
__global__ __launch_bounds__(256) void k_buck(const int* __restrict__ src, const int* __restrict__ dst,
                                              const int* __restrict__ histA, const int* __restrict__ bbase,
                                              int2* __restrict__ ebuf) {
  __shared__ int cur[NBK];
  int t = threadIdx.x, blk = blockIdx.x;
  for (int i = t; i < NBK; i += 256) cur[i] = histA[i * NBLK_A + blk] + bbase[i];
  __syncthreads();
  int e0 = blk * CHUNK_A, e1 = min(ET, e0 + CHUNK_A);
  for (int e = e0 + t; e < e1; e += 256) {
    int s = src[e], d = dst[e];
    int pos = atomicAdd(&cur[d >> BSH], 1);
    ebuf[pos] = make_int2(s, d);
  }
}

// per-bucket fine pass: count/scan/scatter in LDS, emit row_ptr + adj
__global__ __launch_bounds__(256) void k_fine(const int2* __restrict__ ebuf, const int* __restrict__ bbase,
                                              int* __restrict__ rp, int* __restrict__ adj) {
  __shared__ int cnt[256];
  __shared__ int sh[256];
  __shared__ int cur[256];
  int b = blockIdx.x, t = threadIdx.x;
  int eb0 = bbase[b], eb1 = bbase[b + 1];
  cnt[t] = 0;
  __syncthreads();
  for (int e = eb0 + t; e < eb1; e += 256) atomicAdd(&cnt[ebuf[e].y & 255], 1);
  __syncthreads();
  int v = cnt[t];
  sh[t] = v;
  __syncthreads();
  for (int off = 1; off < 256; off <<= 1) {
    int xv = (t >= off) ? sh[t - off] : 0;
    __syncthreads();
    sh[t] += xv;
    __syncthreads();
  }
  int start = eb0 + sh[t] - v;
  cur[t] = start;
  int node = (b << BSH) + t;
  if (node < NT) rp[node] = start;
  if (node == NT - 1) rp[NT] = ET;
  __syncthreads();
  for (int e = eb0 + t; e < eb1; e += 256) {
    int2 p = ebuf[e];
    int pos = atomicAdd(&cur[p.y & 255], 1);
    adj[pos] = p.x;
  }
}

// ---------------- prep: AB[k][j] = sum_c W1[k][h*32+c] * a[h][c]  (j<4: src, j>=4: dst) ----------------
__global__ void k_prep(const float* __restrict__ W1, const float* __restrict__ as1,
                       const float* __restrict__ ad1, float* __restrict__ AB) {
  int t = threadIdx.x;  // 256
  int k = t >> 3, j = t & 7;
  const float* a = (j < 4) ? as1 : ad1;
  int h = j & 3;
  float s = 0.0f;
  for (int c = 0; c < 32; ++c) s += W1[k * 128 + h * 32 + c] * a[h * 32 + c];
  AB[t] = s;  // AB[k*8 + j]
}

// ---------------- att1: es1/ed1 = x @ AB (N x 32 x 8) ----------------
__global__ __launch_bounds__(256) void k_att1(const float* __restrict__ x, const float* __restrict__ AB,
                                              float* __restrict__ es, float* __restrict__ ed) {
  __shared__ float xsh[32 * 33];
  __shared__ float absh[256];
  int t = threadIdx.x;
  int n0 = blockIdx.x * 32;
  absh[t] = AB[t];
  for (int i = t; i < 1024; i += 256) {
    int ln = i >> 5, k = i & 31;
    int node = n0 + ln;
    xsh[ln * 33 + k] = (node < NT) ? x[node * 32 + k] : 0.0f;
  }
  __syncthreads();
  int ln = t >> 3, j = t & 7;
  int node = n0 + ln;
  if (node < NT) {
    float s = 0.0f;
#pragma unroll
    for (int k = 0; k < 32; ++k) s += xsh[ln * 33 + k] * absh[k * 8 + j];
    if (j < 4) es[node * 4 + j] = s;
    else ed[node * 4 + (j - 4)] = s;
  }
}

// ---------------- agg1f: fused L1 aggregate + L1 matvec + ELU + L2 GEMM + L2 logits ----------------
__global__ __launch_bounds__(256) void k_agg1f(
    const int* __restrict__ rp, const int* __restrict__ adj,
    const float* __restrict__ es, const float* __restrict__ ed,
    const float* __restrict__ x,
    const float* __restrict__ W1, const float* __restrict__ b1,
    const float* __restrict__ W2,
    const float* __restrict__ as2, const float* __restrict__ ad2,
    float* __restrict__ h2, float* __restrict__ es2, float* __restrict__ ed2) {
  __shared__ int sbuf[8][34];
  __shared__ f4 wbufv[8][34];
  __shared__ float ysh[8][132];   // [ns][h*33+k]
  __shared__ float osh[8][132];   // [ns][kg*33+kk]
  int t = threadIdx.x;
  int wv = t >> 6, l = t & 63;
  int g = l >> 5, j = l & 31;
  int ns = wv * 2 + g;
  int n = blockIdx.x * 8 + ns;
  bool valid = (n < NT);
  int nc = valid ? n : NT - 1;
  const f4* es4 = (const f4*)es;
  int rs = rp[nc], re = rp[nc + 1];
  int deg = re - rs;
  f4 edn = ((const f4*)ed)[nc];
  f4 esn = es4[nc];
  float sv[4];
#pragma unroll
  for (int h = 0; h < 4; ++h) sv[h] = __expf(lrelu(esn[h] + edn[h]));
  int eg2 = j >> 3, q = j & 7;
  f4 a0 = {0,0,0,0}, a1 = {0,0,0,0}, a2 = {0,0,0,0}, a3 = {0,0,0,0};

  if (deg <= 32) {
    float ex[4] = {0.0f, 0.0f, 0.0f, 0.0f};
    if (j < deg) {
      int s = adj[rs + j];
      sbuf[ns][j] = s;
      f4 ev = es4[s];
#pragma unroll
      for (int h = 0; h < 4; ++h) ex[h] = __expf(lrelu(ev[h] + edn[h]));
    }
    float d[4] = {ex[0], ex[1], ex[2], ex[3]};
#pragma unroll
    for (int off = 1; off <= 16; off <<= 1)
#pragma unroll
      for (int h = 0; h < 4; ++h) d[h] += __shfl_xor(d[h], off);
    float inv[4];
#pragma unroll
    for (int h = 0; h < 4; ++h) inv[h] = 1.0f / (d[h] + sv[h]);
    if (j < deg) {
      f4 w4;
#pragma unroll
      for (int h = 0; h < 4; ++h) w4[h] = ex[h] * inv[h];
      wbufv[ns][j] = w4;
    }
    if (j == 0) {
      sbuf[ns][deg] = nc;
      f4 w4;
#pragma unroll
      for (int h = 0; h < 4; ++h) w4[h] = sv[h] * inv[h];
      wbufv[ns][deg] = w4;
    }
    __builtin_amdgcn_wave_barrier();
    for (int e = eg2; e <= deg; e += 4) {
      f4 xv = *(const f4*)&x[sbuf[ns][e] * 32 + 4 * q];
      f4 w4 = wbufv[ns][e];
      a0 += w4.x * xv; a1 += w4.y * xv; a2 += w4.z * xv; a3 += w4.w * xv;
    }
  } else {
    // generic (deg > 32, rare): no-max two-pass chunked
    float d[4] = {0.0f, 0.0f, 0.0f, 0.0f};
    for (int jj = rs + j; jj < re; jj += 32) {
      f4 ev = es4[adj[jj]];
#pragma unroll
      for (int h = 0; h < 4; ++h) d[h] += __expf(lrelu(ev[h] + edn[h]));
    }
#pragma unroll
    for (int off = 1; off <= 16; off <<= 1)
#pragma unroll
      for (int h = 0; h < 4; ++h) d[h] += __shfl_xor(d[h], off);
    float inv[4];
#pragma unroll
    for (int h = 0; h < 4; ++h) inv[h] = 1.0f / (d[h] + sv[h]);
    for (int base = rs; base < re; base += 32) {
      int cnt = min(32, re - base);
      if (j < cnt) {
        int s = adj[base + j];
        sbuf[ns][j] = s;
        f4 ev = es4[s];
        f4 w4;
#pragma unroll
        for (int h = 0; h < 4; ++h) w4[h] = __expf(lrelu(ev[h] + edn[h])) * inv[h];
        wbufv[ns][j] = w4;
      }
      __builtin_amdgcn_wave_barrier();
      for (int e = eg2; e < cnt; e += 4) {
        f4 xv = *(const f4*)&x[sbuf[ns][e] * 32 + 4 * q];
        f4 w4 = wbufv[ns][e];
        a0 += w4.x * xv; a1 += w4.y * xv; a2 += w4.z * xv; a3 += w4.w * xv;
      }
      __builtin_amdgcn_wave_barrier();
    }
    if (eg2 == 0) {
      f4 xv = *(const f4*)&x[nc * 32 + 4 * q];
      a0 += sv[0] * inv[0] * xv; a1 += sv[1] * inv[1] * xv;
      a2 += sv[2] * inv[2] * xv; a3 += sv[3] * inv[3] * xv;
    }
  }

  // reduce across 4 edge-groups (xor 8, 16 stay within each 32-half)
#pragma unroll
  for (int off = 8; off <= 16; off <<= 1) {
#pragma unroll
    for (int cc = 0; cc < 4; ++cc) {
      a0[cc] += __shfl_xor(a0[cc], off);
      a1[cc] += __shfl_xor(a1[cc], off);
      a2[cc] += __shfl_xor(a2[cc], off);
      a3[cc] += __shfl_xor(a3[cc], off);
    }
  }
  if (eg2 == 0) {
    *(f4*)&ysh[ns][0 * 33 + 4 * q] = a0;
    *(f4*)&ysh[ns][1 * 33 + 4 * q] = a1;
    *(f4*)&ysh[ns][2 * 33 + 4 * q] = a2;
    *(f4*)&ysh[ns][3 * 33 + 4 * q] = a3;
  }
  __syncthreads();

  // matvec1 + ELU, block-wide: thread t -> node ns2=t>>5, channels ch..ch+3
  {
    int ns2 = t >> 5, j2 = t & 31;
    int ch = j2 * 4, hh = j2 >> 3;
    f4 o = {0,0,0,0};
#pragma unroll
    for (int k = 0; k < 32; ++k) {
      o += ysh[ns2][hh * 33 + k] * *(const f4*)&W1[k * 128 + ch];
    }
    o += *(const f4*)&b1[ch];
#pragma unroll
    for (int cc = 0; cc < 4; ++cc) o[cc] = elu1(o[cc]);
    *(f4*)&osh[ns2][(ch >> 5) * 33 + (ch & 31)] = o;
  }
  __syncthreads();

  // matvec2, block-wide: thread t -> node ns2, k-group kg, channels c4..c4+3
  {
    int ns2 = t >> 5, j2 = t & 31;
    int kg = j2 >> 3, c4 = (j2 & 7) * 4;
    int n2 = blockIdx.x * 8 + ns2;
    bool v2 = (n2 < NT);
    f4 p = {0,0,0,0};
#pragma unroll
    for (int kk = 0; kk < 32; ++kk) {
      p += osh[ns2][kg * 33 + kk] * *(const f4*)&W2[(kg * 32 + kk) * 32 + c4];
    }
#pragma unroll
    for (int off = 8; off <= 16; off <<= 1)
#pragma unroll
      for (int cc = 0; cc < 4; ++cc) p[cc] += __shfl_xor(p[cc], off);
    if (kg == 0) {
      if (v2) *(f4*)&h2[n2 * 32 + c4] = p;
      f4 av = *(const f4*)&as2[c4];
      f4 dv = *(const f4*)&ad2[c4];
      float ps = p.x * av.x + p.y * av.y + p.z * av.z + p.w * av.w;
      float pd = p.x * dv.x + p.y * dv.y + p.z * dv.z + p.w * dv.w;
#pragma unroll
      for (int off = 1; off <= 4; off <<= 1) {
        ps += __shfl_xor(ps, off);
        pd += __shfl_xor(pd, off);
      }
      if ((j2 & 7) == 0 && v2) { es2[n2] = ps; ed2[n2] = pd; }
    }
  }
}

// ---------------- agg2: 2 nodes/wave, no-max softmax, fused h2o.Wc -> z ----------------
__global__ __launch_bounds__(256) void k_agg2(const int* __restrict__ rp, const int* __restrict__ adj,
                                              const float* __restrict__ es, const float* __restrict__ ed,
                                              const float* __restrict__ h, const float* __restrict__ b2,
                                              const float* __restrict__ Wc, float* __restrict__ z) {
  __shared__ int sbuf[8][34];
  __shared__ float wsh[8][34];
  int t = threadIdx.x;
  int wv = t >> 6, l = t & 63;
  int g = l >> 5, j = l & 31;
  int ns = wv * 2 + g;
  int n = blockIdx.x * 8 + ns;
  if (n >= NT) return;
  int rs = rp[n], re = rp[n + 1];
  int deg = re - rs;
  float edn = ed[n];
  float sv = __expf(lrelu(es[n] + edn));
  int eg2 = j >> 3, q = j & 7;
  f4 acc = {0,0,0,0};

  if (deg <= 32) {
    float ex = 0.0f;
    if (j < deg) {
      int s = adj[rs + j];
      sbuf[ns][j] = s;
      ex = __expf(lrelu(es[s] + edn));
    }
    float d = ex;
#pragma unroll
    for (int off = 1; off <= 16; off <<= 1) d += __shfl_xor(d, off);
    float inv = 1.0f / (d + sv);
    if (j < deg) wsh[ns][j] = ex * inv;
    if (j == 0) { sbuf[ns][deg] = n; wsh[ns][deg] = sv * inv; }
    __builtin_amdgcn_wave_barrier();
    for (int e = eg2; e <= deg; e += 4) {
      acc += wsh[ns][e] * *(const f4*)&h[sbuf[ns][e] * 32 + 4 * q];
    }
  } else {
    float d = 0.0f;
    for (int jj = rs + j; jj < re; jj += 32) d += __expf(lrelu(es[adj[jj]] + edn));
#pragma unroll
    for (int off = 1; off <= 16; off <<= 1) d += __shfl_xor(d, off);
    float inv = 1.0f / (d + sv);
    for (int base = rs; base < re; base += 32) {
      int cnt = min(32, re - base);
      if (j < cnt) {
        int s = adj[base + j];
        sbuf[ns][j] = s;
        wsh[ns][j] = __expf(lrelu(es[s] + edn)) * inv;
      }
      __builtin_amdgcn_wave_barrier();
      for (int e = eg2; e < cnt; e += 4) {
        acc += wsh[ns][e] * *(const f4*)&h[sbuf[ns][e] * 32 + 4 * q];
      }
      __builtin_amdgcn_wave_barrier();
    }
    if (eg2 == 0) acc += sv * inv * *(const f4*)&h[n * 32 + 4 * q];
  }

#pragma unroll
  for (int off = 8; off <= 16; off <<= 1)
#pragma unroll
    for (int cc = 0; cc < 4; ++cc) acc[cc] += __shfl_xor(acc[cc], off);
  if (eg2 == 0) {
    f4 o = acc + *(const f4*)&b2[4 * q];
#pragma unroll
    for (int cc = 0; cc < 4; ++cc) o[cc] = elu1(o[cc]);
    f4 wc = *(const f4*)&Wc[4 * q];
    float zz = o.x * wc.x + o.y * wc.y + o.z * wc.z + o.w * wc.w;
#pragma unroll
    for (int off = 1; off <= 4; off <<= 1) zz += __shfl_xor(zz, off);
    if (q == 0) z[n] = zz;
  }
}

// ---------------- pooling: one block per graph, sums scalar z ----------------
__global__ __launch_bounds__(256) void k_poolz(const float* __restrict__ z, const int* __restrict__ batch,
                                               const float* __restrict__ bc, float* __restrict__ out) {
  int g = blockIdx.x;
  int lo = 0, hi = NT;
  while (lo < hi) { int mid = (lo + hi) >> 1; if (batch[mid] < g) lo = mid + 1; else hi = mid; }
  int start = lo;
  hi = NT;
  while (lo < hi) { int mid = (lo + hi) >> 1; if (batch[mid] < g + 1) lo = mid + 1; else hi = mid; }
  int end = lo;

  int t = threadIdx.x;
  float s = 0.0f;
  for (int n = start + t; n < end; n += 256) s += z[n];
#pragma unroll
  for (int off = 1; off <= 32; off <<= 1) s += __shfl_xor(s, off);
  __shared__ float sh[4];
  if ((t & 63) == 0) sh[t >> 6] = s;
  __syncthreads();
  if (t == 0) {
    float tot = sh[0] + sh[1] + sh[2] + sh[3];
    float cnt = (float)(end - start);
    out[g] = tot / fmaxf(cnt, 1.0f) + bc[0];
  }
}

extern "C" void kernel_launch(void* const* d_in, const int* in_sizes, int n_in,
                              void* d_out, int out_size, void* d_ws, size_t ws_size,
                              hipStream_t stream) {
  const float* x = (const float*)d_in[0];
  const int* ei = (const int*)d_in[1];
  const int* src = ei;
  const int* dst = ei + ET;
  const int* batch = (const int*)d_in[2];
  const float* W1 = (const float*)d_in[3];
  const float* asrc1 = (const float*)d_in[4];
  const float* adst1 = (const float*)d_in[5];
  const float* b1 = (const float*)d_in[6];
  const float* W2 = (const float*)d_in[7];
  const float* asrc2 = (const float*)d_in[8];
  const float* adst2 = (const float*)d_in[9];
  const float* b2 = (const float*)d_in[10];
  const float* Wc = (const float*)d_in[11];
  const float* bc = (const float*)d_in[12];
  float* out = (float*)d_out;
  char* ws = (char*)d_ws;

  int* row_ptr = (int*)(ws + 0);          // 400004 -> pad 400128
  int* histA = (int*)(ws + 400128);       // 391*256*4 = 400384 -> 800512
  int* btot = (int*)(ws + 800512);        // 1564 -> pad 802112
  int* bbase = (int*)(ws + 802112);       // 1568 -> pad 803712
  float* AB = (float*)(ws + 803712);      // 1024 -> 804736
  int2* ebuf = (int2*)(ws + 804736);      // 12.8MB -> 13604736
  int* adj = (int*)(ws + 13604736);       // 6.4MB -> 20004736
  float* es1 = (float*)(ws + 20004736);   // 1.6MB (16B aligned)
  float* ed1 = (float*)(ws + 21604736);   // 1.6MB
  float* es2 = (float*)(ws + 23204736);   // 400KB
  float* ed2 = (float*)(ws + 23604736);   // 400KB
  float* h2 = (float*)(ws + 24004736);    // 12.8MB -> 36804736
  float* z = (float*)(ws + 36804736);     // 400KB

  // CSR build (bucketed, no global atomics, no memset needed)
  k_histA<<<NBLK_A, 256, 0, stream>>>(dst, histA);
  k_scanB<<<NBK, 256, 0, stream>>>(histA, btot);
  k_scanC<<<1, 512, 0, stream>>>(btot, bbase);
  k_buck<<<NBLK_A, 256, 0, stream>>>(src, dst, histA, bbase, ebuf);
  k_fine<<<NBK, 256, 0, stream>>>(ebuf, bbase, row_ptr, adj);

  // layer 1 attention logits (tiny projection, no h1 materialization)
  k_prep<<<1, 256, 0, stream>>>(W1, asrc1, adst1, AB);
  k_att1<<<(NT + 31) / 32, 256, 0, stream>>>(x, AB, es1, ed1);

  // fused: L1 aggregate (input space) + L1 matvec + ELU + L2 GEMM + L2 logits
  k_agg1f<<<(NT + 7) / 8, 256, 0, stream>>>(row_ptr, adj, es1, ed1, x, W1, b1, W2,
                                            asrc2, adst2, h2, es2, ed2);

  // layer 2 aggregation + ELU + classifier dot (z per node)
  k_agg2<<<(NT + 7) / 8, 256, 0, stream>>>(row_ptr, adj, es2, ed2, h2, b2, Wc, z);

  // pool + bias
  k_poolz<<<GT, 256, 0, stream>>>(z, batch, bc, out);
}

// Round 18
// 219.817 us; speedup vs baseline: 1.2254x; 1.0100x over previous
//
#include <hip/hip_runtime.h>
#include <math.h>

#define NT 100000
#define ET 1600000
#define GT 128
#define NBK 391      // dst>>8 buckets (256 nodes each)
#define BSH 8
#define NBLK_A 256   // blocks in hist/bucketize passes
#define CHUNK_A 6250 // ET / NBLK_A

typedef float f4 __attribute__((ext_vector_type(4)));

__device__ __forceinline__ float lrelu(float v) { return v > 0.0f ? v : 0.2f * v; }
__device__ __forceinline__ float elu1(float v) { return v > 0.0f ? v : __expf(v) - 1.0f; }

// ---------------- CSR build: bucketed two-level, no global atomics ----------------
__global__ __launch_bounds__(256) void k_histA(const int* __restrict__ dst, int* __restrict__ histA) {
  __shared__ int histL[NBK];
  int t = threadIdx.x, blk = blockIdx.x;
  for (int i = t; i < NBK; i += 256) histL[i] = 0;
  __syncthreads();
  int e0 = blk * CHUNK_A, e1 = min(ET, e0 + CHUNK_A);
  for (int e = e0 + t; e < e1; e += 256) atomicAdd(&histL[dst[e] >> BSH], 1);
  __syncthreads();
  for (int i = t; i < NBK; i += 256) histA[i * NBLK_A + blk] = histL[i];
}

__global__ __launch_bounds__(256) void k_scanB(int* __restrict__ histA, int* __restrict__ btot) {
  __shared__ int sh[256];
  int b = blockIdx.x, t = threadIdx.x;
  int v = histA[b * NBLK_A + t];
  sh[t] = v;
  __syncthreads();
  for (int off = 1; off < 256; off <<= 1) {
    int xv = (t >= off) ? sh[t - off] : 0;
    __syncthreads();
    sh[t] += xv;
    __syncthreads();
  }
  histA[b * NBLK_A + t] = sh[t] - v;
  if (t == 255) btot[b] = sh[255];
}

__global__ __launch_bounds__(512) void k_scanC(const int* __restrict__ btot, int* __restrict__ bbase) {
  __shared__ int sh[512];
  int t = threadIdx.x;
  int v = (t < NBK) ? btot[t] : 0;
  sh[t] = v;
  __syncthreads();
  for (int off = 1; off < 512; off <<= 1) {
    int xv = (t >= off) ? sh[t - off] : 0;
    __syncthreads();
    sh[t] += xv;
    __syncthreads();
  }
  if (t < NBK) bbase[t] = sh[t] - v;
  if (t == 0) bbase[NBK] = ET;
}

// bucketize edges into ebuf (LDS cursors; writes cluster per bucket region)
__global__ __launch_bounds__(256) void k_buck(const int* __restrict__ src, const int* __restrict__ dst,
                                              const int* __restrict__ histA, const int* __restrict__ bbase,
                                              int2* __restrict__ ebuf) {
  __shared__ int cur[NBK];
  int t = threadIdx.x, blk = blockIdx.x;
  for (int i = t; i < NBK; i += 256) cur[i] = histA[i * NBLK_A + blk] + bbase[i];
  __syncthreads();
  int e0 = blk * CHUNK_A, e1 = min(ET, e0 + CHUNK_A);
  for (int e = e0 + t; e < e1; e += 256) {
    int s = src[e], d = dst[e];
    int pos = atomicAdd(&cur[d >> BSH], 1);
    ebuf[pos] = make_int2(s, d);
  }
}

// per-bucket fine pass: count/scan/scatter in LDS, emit row_ptr + adj
__global__ __launch_bounds__(256) void k_fine(const int2* __restrict__ ebuf, const int* __restrict__ bbase,
                                              int* __restrict__ rp, int* __restrict__ adj) {
  __shared__ int cnt[256];
  __shared__ int sh[256];
  __shared__ int cur[256];
  int b = blockIdx.x, t = threadIdx.x;
  int eb0 = bbase[b], eb1 = bbase[b + 1];
  cnt[t] = 0;
  __syncthreads();
  for (int e = eb0 + t; e < eb1; e += 256) atomicAdd(&cnt[ebuf[e].y & 255], 1);
  __syncthreads();
  int v = cnt[t];
  sh[t] = v;
  __syncthreads();
  for (int off = 1; off < 256; off <<= 1) {
    int xv = (t >= off) ? sh[t - off] : 0;
    __syncthreads();
    sh[t] += xv;
    __syncthreads();
  }
  int start = eb0 + sh[t] - v;
  cur[t] = start;
  int node = (b << BSH) + t;
  if (node < NT) rp[node] = start;
  if (node == NT - 1) rp[NT] = ET;
  __syncthreads();
  for (int e = eb0 + t; e < eb1; e += 256) {
    int2 p = ebuf[e];
    int pos = atomicAdd(&cur[p.y & 255], 1);
    adj[pos] = p.x;
  }
}

// ---------------- prep: AB[k][j] = sum_c W1[k][h*32+c] * a[h][c]  (j<4: src, j>=4: dst) ----------------
__global__ void k_prep(const float* __restrict__ W1, const float* __restrict__ as1,
                       const float* __restrict__ ad1, float* __restrict__ AB) {
  int t = threadIdx.x;  // 256
  int k = t >> 3, j = t & 7;
  const float* a = (j < 4) ? as1 : ad1;
  int h = j & 3;
  float s = 0.0f;
  for (int c = 0; c < 32; ++c) s += W1[k * 128 + h * 32 + c] * a[h * 32 + c];
  AB[t] = s;  // AB[k*8 + j]
}

// ---------------- att1: es1/ed1 = x @ AB (N x 32 x 8) ----------------
__global__ __launch_bounds__(256) void k_att1(const float* __restrict__ x, const float* __restrict__ AB,
                                              float* __restrict__ es, float* __restrict__ ed) {
  __shared__ float xsh[32 * 33];
  __shared__ float absh[256];
  int t = threadIdx.x;
  int n0 = blockIdx.x * 32;
  absh[t] = AB[t];
  for (int i = t; i < 1024; i += 256) {
    int ln = i >> 5, k = i & 31;
    int node = n0 + ln;
    xsh[ln * 33 + k] = (node < NT) ? x[node * 32 + k] : 0.0f;
  }
  __syncthreads();
  int ln = t >> 3, j = t & 7;
  int node = n0 + ln;
  if (node < NT) {
    float s = 0.0f;
#pragma unroll
    for (int k = 0; k < 32; ++k) s += xsh[ln * 33 + k] * absh[k * 8 + j];
    if (j < 4) es[node * 4 + j] = s;
    else ed[node * 4 + (j - 4)] = s;
  }
}

// ---------------- agg1f: fused L1 aggregate + L1 matvec + ELU + L2 GEMM + L2 logits ----------------
// Gather: 2 nodes/wave (r10 structure). Matvecs: channel-partitioned — each wave
// computes ALL 8 nodes for 1/4 of channels, so W1/W2 are streamed from L1 once
// per BLOCK (32KB) instead of once per wave (128KB).
__global__ __launch_bounds__(256) void k_agg1f(
    const int* __restrict__ rp, const int* __restrict__ adj,
    const float* __restrict__ es, const float* __restrict__ ed,
    const float* __restrict__ x,
    const float* __restrict__ W1, const float* __restrict__ b1,
    const float* __restrict__ W2,
    const float* __restrict__ as2, const float* __restrict__ ad2,
    float* __restrict__ h2, float* __restrict__ es2, float* __restrict__ ed2) {
  __shared__ int sbuf[8][34];
  __shared__ f4 wbufv[8][34];
  __shared__ float ysh[8][132];   // [ns][h*33+k]
  __shared__ float osh[8][132];   // [ns][(c>>5)*33 + (c&31)]
  __shared__ float psh[4][8][33]; // [wv][nd][c] partial matvec2 sums
  int t = threadIdx.x;
  int wv = t >> 6, l = t & 63;
  int g = l >> 5, j = l & 31;
  int ns = wv * 2 + g;
  int n = blockIdx.x * 8 + ns;
  bool valid = (n < NT);
  int nc = valid ? n : NT - 1;
  const f4* es4 = (const f4*)es;
  int rs = rp[nc], re = rp[nc + 1];
  int deg = re - rs;
  f4 edn = ((const f4*)ed)[nc];
  f4 esn = es4[nc];
  float sv[4];
#pragma unroll
  for (int h = 0; h < 4; ++h) sv[h] = __expf(lrelu(esn[h] + edn[h]));
  int eg2 = j >> 3, q = j & 7;
  f4 a0 = {0,0,0,0}, a1 = {0,0,0,0}, a2 = {0,0,0,0}, a3 = {0,0,0,0};

  if (deg <= 32) {
    float ex[4] = {0.0f, 0.0f, 0.0f, 0.0f};
    if (j < deg) {
      int s = adj[rs + j];
      sbuf[ns][j] = s;
      f4 ev = es4[s];
#pragma unroll
      for (int h = 0; h < 4; ++h) ex[h] = __expf(lrelu(ev[h] + edn[h]));
    }
    float d[4] = {ex[0], ex[1], ex[2], ex[3]};
#pragma unroll
    for (int off = 1; off <= 16; off <<= 1)
#pragma unroll
      for (int h = 0; h < 4; ++h) d[h] += __shfl_xor(d[h], off);
    float inv[4];
#pragma unroll
    for (int h = 0; h < 4; ++h) inv[h] = 1.0f / (d[h] + sv[h]);
    if (j < deg) {
      f4 w4;
#pragma unroll
      for (int h = 0; h < 4; ++h) w4[h] = ex[h] * inv[h];
      wbufv[ns][j] = w4;
    }
    if (j == 0) {
      sbuf[ns][deg] = nc;
      f4 w4;
#pragma unroll
      for (int h = 0; h < 4; ++h) w4[h] = sv[h] * inv[h];
      wbufv[ns][deg] = w4;
    }
    __builtin_amdgcn_wave_barrier();
    for (int e = eg2; e <= deg; e += 4) {
      f4 xv = *(const f4*)&x[sbuf[ns][e] * 32 + 4 * q];
      f4 w4 = wbufv[ns][e];
      a0 += w4.x * xv; a1 += w4.y * xv; a2 += w4.z * xv; a3 += w4.w * xv;
    }
  } else {
    // generic (deg > 32, rare): no-max two-pass chunked
    float d[4] = {0.0f, 0.0f, 0.0f, 0.0f};
    for (int jj = rs + j; jj < re; jj += 32) {
      f4 ev = es4[adj[jj]];
#pragma unroll
      for (int h = 0; h < 4; ++h) d[h] += __expf(lrelu(ev[h] + edn[h]));
    }
#pragma unroll
    for (int off = 1; off <= 16; off <<= 1)
#pragma unroll
      for (int h = 0; h < 4; ++h) d[h] += __shfl_xor(d[h], off);
    float inv[4];
#pragma unroll
    for (int h = 0; h < 4; ++h) inv[h] = 1.0f / (d[h] + sv[h]);
    for (int base = rs; base < re; base += 32) {
      int cnt = min(32, re - base);
      if (j < cnt) {
        int s = adj[base + j];
        sbuf[ns][j] = s;
        f4 ev = es4[s];
        f4 w4;
#pragma unroll
        for (int h = 0; h < 4; ++h) w4[h] = __expf(lrelu(ev[h] + edn[h])) * inv[h];
        wbufv[ns][j] = w4;
      }
      __builtin_amdgcn_wave_barrier();
      for (int e = eg2; e < cnt; e += 4) {
        f4 xv = *(const f4*)&x[sbuf[ns][e] * 32 + 4 * q];
        f4 w4 = wbufv[ns][e];
        a0 += w4.x * xv; a1 += w4.y * xv; a2 += w4.z * xv; a3 += w4.w * xv;
      }
      __builtin_amdgcn_wave_barrier();
    }
    if (eg2 == 0) {
      f4 xv = *(const f4*)&x[nc * 32 + 4 * q];
      a0 += sv[0] * inv[0] * xv; a1 += sv[1] * inv[1] * xv;
      a2 += sv[2] * inv[2] * xv; a3 += sv[3] * inv[3] * xv;
    }
  }

  // reduce across 4 edge-groups (xor 8, 16 stay within each 32-half)
#pragma unroll
  for (int off = 8; off <= 16; off <<= 1) {
#pragma unroll
    for (int cc = 0; cc < 4; ++cc) {
      a0[cc] += __shfl_xor(a0[cc], off);
      a1[cc] += __shfl_xor(a1[cc], off);
      a2[cc] += __shfl_xor(a2[cc], off);
      a3[cc] += __shfl_xor(a3[cc], off);
    }
  }
  if (eg2 == 0) {
    *(f4*)&ysh[ns][0 * 33 + 4 * q] = a0;
    *(f4*)&ysh[ns][1 * 33 + 4 * q] = a1;
    *(f4*)&ysh[ns][2 * 33 + 4 * q] = a2;
    *(f4*)&ysh[ns][3 * 33 + 4 * q] = a3;
  }
  __syncthreads();

  // matvec1 + ELU: wave wv owns head wv (channels wv*32..+31) for ALL 8 nodes.
  // Per k: 8 broadcast f4 W1 loads (128B/wave) -> W1 read once per block.
  {
    int nd = l >> 3, i8 = l & 7;
    int ch = wv * 32 + i8 * 4;
    f4 o = {0,0,0,0};
#pragma unroll
    for (int k = 0; k < 32; ++k) {
      o += ysh[nd][wv * 33 + k] * *(const f4*)&W1[k * 128 + ch];
    }
    o += *(const f4*)&b1[ch];
#pragma unroll
    for (int cc = 0; cc < 4; ++cc) o[cc] = elu1(o[cc]);
    *(f4*)&osh[nd][wv * 33 + i8 * 4] = o;
  }
  __syncthreads();

  // matvec2: wave wv owns k-quarter wv (k = wv*32..+31) for all 8 nodes x 32 ch.
  // Per kk: 8 broadcast f4 W2 loads -> W2 read once per block. Partial to psh.
  {
    int nd = l >> 3, i8 = l & 7;
    int c4 = i8 * 4;
    f4 p = {0,0,0,0};
#pragma unroll
    for (int kk = 0; kk < 32; ++kk) {
      p += osh[nd][wv * 33 + kk] * *(const f4*)&W2[(wv * 32 + kk) * 32 + c4];
    }
    psh[wv][nd][c4 + 0] = p.x;
    psh[wv][nd][c4 + 1] = p.y;
    psh[wv][nd][c4 + 2] = p.z;
    psh[wv][nd][c4 + 3] = p.w;
  }
  __syncthreads();

  // cross-wave reduce + epilogue: thread (nd = t>>5, c = t&31)
  {
    int nd = t >> 5, c = t & 31;
    float p = psh[0][nd][c] + psh[1][nd][c] + psh[2][nd][c] + psh[3][nd][c];
    int n2 = blockIdx.x * 8 + nd;
    bool v2 = (n2 < NT);
    if (v2) h2[n2 * 32 + c] = p;
    float ps = p * as2[c], pd = p * ad2[c];
#pragma unroll
    for (int off = 1; off <= 16; off <<= 1) {
      ps += __shfl_xor(ps, off);
      pd += __shfl_xor(pd, off);
    }
    if (c == 0 && v2) { es2[n2] = ps; ed2[n2] = pd; }
  }
}

// ---------------- agg2: 2 nodes/wave, no-max softmax, fused h2o.Wc -> z ----------------
__global__ __launch_bounds__(256) void k_agg2(const int* __restrict__ rp, const int* __restrict__ adj,
                                              const float* __restrict__ es, const float* __restrict__ ed,
                                              const float* __restrict__ h, const float* __restrict__ b2,
                                              const float* __restrict__ Wc, float* __restrict__ z) {
  __shared__ int sbuf[8][34];
  __shared__ float wsh[8][34];
  int t = threadIdx.x;
  int wv = t >> 6, l = t & 63;
  int g = l >> 5, j = l & 31;
  int ns = wv * 2 + g;
  int n = blockIdx.x * 8 + ns;
  if (n >= NT) return;
  int rs = rp[n], re = rp[n + 1];
  int deg = re - rs;
  float edn = ed[n];
  float sv = __expf(lrelu(es[n] + edn));
  int eg2 = j >> 3, q = j & 7;
  f4 acc = {0,0,0,0};

  if (deg <= 32) {
    float ex = 0.0f;
    if (j < deg) {
      int s = adj[rs + j];
      sbuf[ns][j] = s;
      ex = __expf(lrelu(es[s] + edn));
    }
    float d = ex;
#pragma unroll
    for (int off = 1; off <= 16; off <<= 1) d += __shfl_xor(d, off);
    float inv = 1.0f / (d + sv);
    if (j < deg) wsh[ns][j] = ex * inv;
    if (j == 0) { sbuf[ns][deg] = n; wsh[ns][deg] = sv * inv; }
    __builtin_amdgcn_wave_barrier();
    for (int e = eg2; e <= deg; e += 4) {
      acc += wsh[ns][e] * *(const f4*)&h[sbuf[ns][e] * 32 + 4 * q];
    }
  } else {
    float d = 0.0f;
    for (int jj = rs + j; jj < re; jj += 32) d += __expf(lrelu(es[adj[jj]] + edn));
#pragma unroll
    for (int off = 1; off <= 16; off <<= 1) d += __shfl_xor(d, off);
    float inv = 1.0f / (d + sv);
    for (int base = rs; base < re; base += 32) {
      int cnt = min(32, re - base);
      if (j < cnt) {
        int s = adj[base + j];
        sbuf[ns][j] = s;
        wsh[ns][j] = __expf(lrelu(es[s] + edn)) * inv;
      }
      __builtin_amdgcn_wave_barrier();
      for (int e = eg2; e < cnt; e += 4) {
        acc += wsh[ns][e] * *(const f4*)&h[sbuf[ns][e] * 32 + 4 * q];
      }
      __builtin_amdgcn_wave_barrier();
    }
    if (eg2 == 0) acc += sv * inv * *(const f4*)&h[n * 32 + 4 * q];
  }

#pragma unroll
  for (int off = 8; off <= 16; off <<= 1)
#pragma unroll
    for (int cc = 0; cc < 4; ++cc) acc[cc] += __shfl_xor(acc[cc], off);
  if (eg2 == 0) {
    f4 o = acc + *(const f4*)&b2[4 * q];
#pragma unroll
    for (int cc = 0; cc < 4; ++cc) o[cc] = elu1(o[cc]);
    f4 wc = *(const f4*)&Wc[4 * q];
    float zz = o.x * wc.x + o.y * wc.y + o.z * wc.z + o.w * wc.w;
#pragma unroll
    for (int off = 1; off <= 4; off <<= 1) zz += __shfl_xor(zz, off);
    if (q == 0) z[n] = zz;
  }
}

// ---------------- pooling: one block per graph, sums scalar z ----------------
__global__ __launch_bounds__(256) void k_poolz(const float* __restrict__ z, const int* __restrict__ batch,
                                               const float* __restrict__ bc, float* __restrict__ out) {
  int g = blockIdx.x;
  int lo = 0, hi = NT;
  while (lo < hi) { int mid = (lo + hi) >> 1; if (batch[mid] < g) lo = mid + 1; else hi = mid; }
  int start = lo;
  hi = NT;
  while (lo < hi) { int mid = (lo + hi) >> 1; if (batch[mid] < g + 1) lo = mid + 1; else hi = mid; }
  int end = lo;

  int t = threadIdx.x;
  float s = 0.0f;
  for (int n = start + t; n < end; n += 256) s += z[n];
#pragma unroll
  for (int off = 1; off <= 32; off <<= 1) s += __shfl_xor(s, off);
  __shared__ float sh[4];
  if ((t & 63) == 0) sh[t >> 6] = s;
  __syncthreads();
  if (t == 0) {
    float tot = sh[0] + sh[1] + sh[2] + sh[3];
    float cnt = (float)(end - start);
    out[g] = tot / fmaxf(cnt, 1.0f) + bc[0];
  }
}

extern "C" void kernel_launch(void* const* d_in, const int* in_sizes, int n_in,
                              void* d_out, int out_size, void* d_ws, size_t ws_size,
                              hipStream_t stream) {
  const float* x = (const float*)d_in[0];
  const int* ei = (const int*)d_in[1];
  const int* src = ei;
  const int* dst = ei + ET;
  const int* batch = (const int*)d_in[2];
  const float* W1 = (const float*)d_in[3];
  const float* asrc1 = (const float*)d_in[4];
  const float* adst1 = (const float*)d_in[5];
  const float* b1 = (const float*)d_in[6];
  const float* W2 = (const float*)d_in[7];
  const float* asrc2 = (const float*)d_in[8];
  const float* adst2 = (const float*)d_in[9];
  const float* b2 = (const float*)d_in[10];
  const float* Wc = (const float*)d_in[11];
  const float* bc = (const float*)d_in[12];
  float* out = (float*)d_out;
  char* ws = (char*)d_ws;

  int* row_ptr = (int*)(ws + 0);          // 400004 -> pad 400128
  int* histA = (int*)(ws + 400128);       // 391*256*4 = 400384 -> 800512
  int* btot = (int*)(ws + 800512);        // 1564 -> pad 802112
  int* bbase = (int*)(ws + 802112);       // 1568 -> pad 803712
  float* AB = (float*)(ws + 803712);      // 1024 -> 804736
  int2* ebuf = (int2*)(ws + 804736);      // 12.8MB -> 13604736
  int* adj = (int*)(ws + 13604736);       // 6.4MB -> 20004736
  float* es1 = (float*)(ws + 20004736);   // 1.6MB (16B aligned)
  float* ed1 = (float*)(ws + 21604736);   // 1.6MB
  float* es2 = (float*)(ws + 23204736);   // 400KB
  float* ed2 = (float*)(ws + 23604736);   // 400KB
  float* h2 = (float*)(ws + 24004736);    // 12.8MB -> 36804736
  float* z = (float*)(ws + 36804736);     // 400KB

  // CSR build (bucketed, no global atomics, no memset needed)
  k_histA<<<NBLK_A, 256, 0, stream>>>(dst, histA);
  k_scanB<<<NBK, 256, 0, stream>>>(histA, btot);
  k_scanC<<<1, 512, 0, stream>>>(btot, bbase);
  k_buck<<<NBLK_A, 256, 0, stream>>>(src, dst, histA, bbase, ebuf);
  k_fine<<<NBK, 256, 0, stream>>>(ebuf, bbase, row_ptr, adj);

  // layer 1 attention logits (tiny projection, no h1 materialization)
  k_prep<<<1, 256, 0, stream>>>(W1, asrc1, adst1, AB);
  k_att1<<<(NT + 31) / 32, 256, 0, stream>>>(x, AB, es1, ed1);

  // fused: L1 aggregate (input space) + L1 matvec + ELU + L2 GEMM + L2 logits
  k_agg1f<<<(NT + 7) / 8, 256, 0, stream>>>(row_ptr, adj, es1, ed1, x, W1, b1, W2,
                                            asrc2, adst2, h2, es2, ed2);

  // layer 2 aggregation + ELU + classifier dot (z per node)
  k_agg2<<<(NT + 7) / 8, 256, 0, stream>>>(row_ptr, adj, es2, ed2, h2, b2, Wc, z);

  // pool + bias
  k_poolz<<<GT, 256, 0, stream>>>(z, batch, bc, out);
}

// Round 19
// 219.685 us; speedup vs baseline: 1.2261x; 1.0006x over previous
//
#include <hip/hip_runtime.h>
#include <math.h>

#define NT 100000
#define ET 1600000
#define GT 128
#define NBK 391      // dst>>8 buckets (256 nodes each)
#define BSH 8
#define NBLK_A 256   // blocks in hist/bucketize passes
#define CHUNK_A 6250 // ET / NBLK_A

typedef float f4 __attribute__((ext_vector_type(4)));

__device__ __forceinline__ float lrelu(float v) { return v > 0.0f ? v : 0.2f * v; }
__device__ __forceinline__ float elu1(float v) { return v > 0.0f ? v : __expf(v) - 1.0f; }

// ---------------- CSR build: bucketed two-level, no global atomics ----------------
__global__ __launch_bounds__(256) void k_histA(const int* __restrict__ dst, int* __restrict__ histA) {
  __shared__ int histL[NBK];
  int t = threadIdx.x, blk = blockIdx.x;
  for (int i = t; i < NBK; i += 256) histL[i] = 0;
  __syncthreads();
  int e0 = blk * CHUNK_A, e1 = min(ET, e0 + CHUNK_A);
  for (int e = e0 + t; e < e1; e += 256) atomicAdd(&histL[dst[e] >> BSH], 1);
  __syncthreads();
  for (int i = t; i < NBK; i += 256) histA[i * NBLK_A + blk] = histL[i];
}

__global__ __launch_bounds__(256) void k_scanB(int* __restrict__ histA, int* __restrict__ btot) {
  __shared__ int sh[256];
  int b = blockIdx.x, t = threadIdx.x;
  int v = histA[b * NBLK_A + t];
  sh[t] = v;
  __syncthreads();
  for (int off = 1; off < 256; off <<= 1) {
    int xv = (t >= off) ? sh[t - off] : 0;
    __syncthreads();
    sh[t] += xv;
    __syncthreads();
  }
  histA[b * NBLK_A + t] = sh[t] - v;
  if (t == 255) btot[b] = sh[255];
}

__global__ __launch_bounds__(512) void k_scanC(const int* __restrict__ btot, int* __restrict__ bbase) {
  __shared__ int sh[512];
  int t = threadIdx.x;
  int v = (t < NBK) ? btot[t] : 0;
  sh[t] = v;
  __syncthreads();
  for (int off = 1; off < 512; off <<= 1) {
    int xv = (t >= off) ? sh[t - off] : 0;
    __syncthreads();
    sh[t] += xv;
    __syncthreads();
  }
  if (t < NBK) bbase[t] = sh[t] - v;
  if (t == 0) bbase[NBK] = ET;
}

// bucketize edges into ebuf (LDS cursors; writes cluster per bucket region)
__global__ __launch_bounds__(256) void k_buck(const int* __restrict__ src, const int* __restrict__ dst,
                                              const int* __restrict__ histA, const int* __restrict__ bbase,
                                              int2* __restrict__ ebuf) {
  __shared__ int cur[NBK];
  int t = threadIdx.x, blk = blockIdx.x;
  for (int i = t; i < NBK; i += 256) cur[i] = histA[i * NBLK_A + blk] + bbase[i];
  __syncthreads();
  int e0 = blk * CHUNK_A, e1 = min(ET, e0 + CHUNK_A);
  for (int e = e0 + t; e < e1; e += 256) {
    int s = src[e], d = dst[e];
    int pos = atomicAdd(&cur[d >> BSH], 1);
    ebuf[pos] = make_int2(s, d);
  }
}

// per-bucket fine pass: count/scan/scatter in LDS, emit row_ptr + adj
__global__ __launch_bounds__(256) void k_fine(const int2* __restrict__ ebuf, const int* __restrict__ bbase,
                                              int* __restrict__ rp, int* __restrict__ adj) {
  __shared__ int cnt[256];
  __shared__ int sh[256];
  __shared__ int cur[256];
  int b = blockIdx.x, t = threadIdx.x;
  int eb0 = bbase[b], eb1 = bbase[b + 1];
  cnt[t] = 0;
  __syncthreads();
  for (int e = eb0 + t; e < eb1; e += 256) atomicAdd(&cnt[ebuf[e].y & 255], 1);
  __syncthreads();
  int v = cnt[t];
  sh[t] = v;
  __syncthreads();
  for (int off = 1; off < 256; off <<= 1) {
    int xv = (t >= off) ? sh[t - off] : 0;
    __syncthreads();
    sh[t] += xv;
    __syncthreads();
  }
  int start = eb0 + sh[t] - v;
  cur[t] = start;
  int node = (b << BSH) + t;
  if (node < NT) rp[node] = start;
  if (node == NT - 1) rp[NT] = ET;
  __syncthreads();
  for (int e = eb0 + t; e < eb1; e += 256) {
    int2 p = ebuf[e];
    int pos = atomicAdd(&cur[p.y & 255], 1);
    adj[pos] = p.x;
  }
}

// ---------------- prep: AB[k][j] = sum_c W1[k][h*32+c] * a[h][c]  (j<4: src, j>=4: dst) ----------------
__global__ void k_prep(const float* __restrict__ W1, const float* __restrict__ as1,
                       const float* __restrict__ ad1, float* __restrict__ AB) {
  int t = threadIdx.x;  // 256
  int k = t >> 3, j = t & 7;
  const float* a = (j < 4) ? as1 : ad1;
  int h = j & 3;
  float s = 0.0f;
  for (int c = 0; c < 32; ++c) s += W1[k * 128 + h * 32 + c] * a[h * 32 + c];
  AB[t] = s;  // AB[k*8 + j]
}

// ---------------- att1: es1/ed1 = x @ AB (N x 32 x 8) ----------------
__global__ __launch_bounds__(256) void k_att1(const float* __restrict__ x, const float* __restrict__ AB,
                                              float* __restrict__ es, float* __restrict__ ed) {
  __shared__ float xsh[32 * 33];
  __shared__ float absh[256];
  int t = threadIdx.x;
  int n0 = blockIdx.x * 32;
  absh[t] = AB[t];
  for (int i = t; i < 1024; i += 256) {
    int ln = i >> 5, k = i & 31;
    int node = n0 + ln;
    xsh[ln * 33 + k] = (node < NT) ? x[node * 32 + k] : 0.0f;
  }
  __syncthreads();
  int ln = t >> 3, j = t & 7;
  int node = n0 + ln;
  if (node < NT) {
    float s = 0.0f;
#pragma unroll
    for (int k = 0; k < 32; ++k) s += xsh[ln * 33 + k] * absh[k * 8 + j];
    if (j < 4) es[node * 4 + j] = s;
    else ed[node * 4 + (j - 4)] = s;
  }
}

// ---------------- agg1f: fused L1 aggregate + L1 matvec + ELU + L2 GEMM + L2 logits ----------------
// Gather: 2 nodes/wave, 4-deep predicated unroll (4 row-loads in flight/lane).
// Matvecs: channel-partitioned (W1/W2 streamed from L1 once per block).
__global__ __launch_bounds__(256) void k_agg1f(
    const int* __restrict__ rp, const int* __restrict__ adj,
    const float* __restrict__ es, const float* __restrict__ ed,
    const float* __restrict__ x,
    const float* __restrict__ W1, const float* __restrict__ b1,
    const float* __restrict__ W2,
    const float* __restrict__ as2, const float* __restrict__ ad2,
    float* __restrict__ h2, float* __restrict__ es2, float* __restrict__ ed2) {
  __shared__ int sbuf[8][34];
  __shared__ f4 wbufv[8][34];
  __shared__ float ysh[8][132];   // [ns][h*33+k]
  __shared__ float osh[8][132];   // [ns][(c>>5)*33 + (c&31)]
  __shared__ float psh[4][8][33]; // [wv][nd][c] partial matvec2 sums
  int t = threadIdx.x;
  int wv = t >> 6, l = t & 63;
  int g = l >> 5, j = l & 31;
  int ns = wv * 2 + g;
  int n = blockIdx.x * 8 + ns;
  bool valid = (n < NT);
  int nc = valid ? n : NT - 1;
  const f4* es4 = (const f4*)es;
  int rs = rp[nc], re = rp[nc + 1];
  int deg = re - rs;
  f4 edn = ((const f4*)ed)[nc];
  f4 esn = es4[nc];
  float sv[4];
#pragma unroll
  for (int h = 0; h < 4; ++h) sv[h] = __expf(lrelu(esn[h] + edn[h]));
  int eg2 = j >> 3, q = j & 7;
  f4 a0 = {0,0,0,0}, a1 = {0,0,0,0}, a2 = {0,0,0,0}, a3 = {0,0,0,0};

  if (deg <= 32) {
    float ex[4] = {0.0f, 0.0f, 0.0f, 0.0f};
    if (j < deg) {
      int s = adj[rs + j];
      sbuf[ns][j] = s;
      f4 ev = es4[s];
#pragma unroll
      for (int h = 0; h < 4; ++h) ex[h] = __expf(lrelu(ev[h] + edn[h]));
    }
    float d[4] = {ex[0], ex[1], ex[2], ex[3]};
#pragma unroll
    for (int off = 1; off <= 16; off <<= 1)
#pragma unroll
      for (int h = 0; h < 4; ++h) d[h] += __shfl_xor(d[h], off);
    float inv[4];
#pragma unroll
    for (int h = 0; h < 4; ++h) inv[h] = 1.0f / (d[h] + sv[h]);
    if (j < deg) {
      f4 w4;
#pragma unroll
      for (int h = 0; h < 4; ++h) w4[h] = ex[h] * inv[h];
      wbufv[ns][j] = w4;
    }
    if (j == 0) {
      sbuf[ns][deg] = nc;
      f4 w4;
#pragma unroll
      for (int h = 0; h < 4; ++h) w4[h] = sv[h] * inv[h];
      wbufv[ns][deg] = w4;
    }
    __builtin_amdgcn_wave_barrier();
    // 4-deep predicated unroll: up to 4 independent row loads in flight per lane
    for (int e0 = eg2; e0 <= deg; e0 += 16) {
#pragma unroll
      for (int i = 0; i < 4; ++i) {
        int e = e0 + i * 4;
        if (e <= deg) {
          f4 xv = *(const f4*)&x[sbuf[ns][e] * 32 + 4 * q];
          f4 w4 = wbufv[ns][e];
          a0 += w4.x * xv; a1 += w4.y * xv; a2 += w4.z * xv; a3 += w4.w * xv;
        }
      }
    }
  } else {
    // generic (deg > 32, rare): no-max two-pass chunked
    float d[4] = {0.0f, 0.0f, 0.0f, 0.0f};
    for (int jj = rs + j; jj < re; jj += 32) {
      f4 ev = es4[adj[jj]];
#pragma unroll
      for (int h = 0; h < 4; ++h) d[h] += __expf(lrelu(ev[h] + edn[h]));
    }
#pragma unroll
    for (int off = 1; off <= 16; off <<= 1)
#pragma unroll
      for (int h = 0; h < 4; ++h) d[h] += __shfl_xor(d[h], off);
    float inv[4];
#pragma unroll
    for (int h = 0; h < 4; ++h) inv[h] = 1.0f / (d[h] + sv[h]);
    for (int base = rs; base < re; base += 32) {
      int cnt = min(32, re - base);
      if (j < cnt) {
        int s = adj[base + j];
        sbuf[ns][j] = s;
        f4 ev = es4[s];
        f4 w4;
#pragma unroll
        for (int h = 0; h < 4; ++h) w4[h] = __expf(lrelu(ev[h] + edn[h])) * inv[h];
        wbufv[ns][j] = w4;
      }
      __builtin_amdgcn_wave_barrier();
      for (int e = eg2; e < cnt; e += 4) {
        f4 xv = *(const f4*)&x[sbuf[ns][e] * 32 + 4 * q];
        f4 w4 = wbufv[ns][e];
        a0 += w4.x * xv; a1 += w4.y * xv; a2 += w4.z * xv; a3 += w4.w * xv;
      }
      __builtin_amdgcn_wave_barrier();
    }
    if (eg2 == 0) {
      f4 xv = *(const f4*)&x[nc * 32 + 4 * q];
      a0 += sv[0] * inv[0] * xv; a1 += sv[1] * inv[1] * xv;
      a2 += sv[2] * inv[2] * xv; a3 += sv[3] * inv[3] * xv;
    }
  }

  // reduce across 4 edge-groups (xor 8, 16 stay within each 32-half)
#pragma unroll
  for (int off = 8; off <= 16; off <<= 1) {
#pragma unroll
    for (int cc = 0; cc < 4; ++cc) {
      a0[cc] += __shfl_xor(a0[cc], off);
      a1[cc] += __shfl_xor(a1[cc], off);
      a2[cc] += __shfl_xor(a2[cc], off);
      a3[cc] += __shfl_xor(a3[cc], off);
    }
  }
  if (eg2 == 0) {
    *(f4*)&ysh[ns][0 * 33 + 4 * q] = a0;
    *(f4*)&ysh[ns][1 * 33 + 4 * q] = a1;
    *(f4*)&ysh[ns][2 * 33 + 4 * q] = a2;
    *(f4*)&ysh[ns][3 * 33 + 4 * q] = a3;
  }
  __syncthreads();

  // matvec1 + ELU: wave wv owns head wv for ALL 8 nodes; W1 read once per block.
  // osh written as 4 scalar stores (2-way max bank aliasing).
  {
    int nd = l >> 3, i8 = l & 7;
    int ch = wv * 32 + i8 * 4;
    f4 o = {0,0,0,0};
#pragma unroll
    for (int k = 0; k < 32; ++k) {
      o += ysh[nd][wv * 33 + k] * *(const f4*)&W1[k * 128 + ch];
    }
    o += *(const f4*)&b1[ch];
#pragma unroll
    for (int cc = 0; cc < 4; ++cc) {
      osh[nd][wv * 33 + i8 * 4 + cc] = elu1(o[cc]);
    }
  }
  __syncthreads();

  // matvec2: wave wv owns k-quarter wv for all 8 nodes x 32 ch; W2 once per block.
  {
    int nd = l >> 3, i8 = l & 7;
    int c4 = i8 * 4;
    f4 p = {0,0,0,0};
#pragma unroll
    for (int kk = 0; kk < 32; ++kk) {
      p += osh[nd][wv * 33 + kk] * *(const f4*)&W2[(wv * 32 + kk) * 32 + c4];
    }
    psh[wv][nd][c4 + 0] = p.x;
    psh[wv][nd][c4 + 1] = p.y;
    psh[wv][nd][c4 + 2] = p.z;
    psh[wv][nd][c4 + 3] = p.w;
  }
  __syncthreads();

  // cross-wave reduce + epilogue: thread (nd = t>>5, c = t&31)
  {
    int nd = t >> 5, c = t & 31;
    float p = psh[0][nd][c] + psh[1][nd][c] + psh[2][nd][c] + psh[3][nd][c];
    int n2 = blockIdx.x * 8 + nd;
    bool v2 = (n2 < NT);
    if (v2) h2[n2 * 32 + c] = p;
    float ps = p * as2[c], pd = p * ad2[c];
#pragma unroll
    for (int off = 1; off <= 16; off <<= 1) {
      ps += __shfl_xor(ps, off);
      pd += __shfl_xor(pd, off);
    }
    if (c == 0 && v2) { es2[n2] = ps; ed2[n2] = pd; }
  }
}

// ---------------- agg2: 2 nodes/wave, no-max softmax, fused h2o.Wc -> z ----------------
__global__ __launch_bounds__(256) void k_agg2(const int* __restrict__ rp, const int* __restrict__ adj,
                                              const float* __restrict__ es, const float* __restrict__ ed,
                                              const float* __restrict__ h, const float* __restrict__ b2,
                                              const float* __restrict__ Wc, float* __restrict__ z) {
  __shared__ int sbuf[8][34];
  __shared__ float wsh[8][34];
  int t = threadIdx.x;
  int wv = t >> 6, l = t & 63;
  int g = l >> 5, j = l & 31;
  int ns = wv * 2 + g;
  int n = blockIdx.x * 8 + ns;
  if (n >= NT) return;
  int rs = rp[n], re = rp[n + 1];
  int deg = re - rs;
  float edn = ed[n];
  float sv = __expf(lrelu(es[n] + edn));
  int eg2 = j >> 3, q = j & 7;
  f4 acc = {0,0,0,0};

  if (deg <= 32) {
    float ex = 0.0f;
    if (j < deg) {
      int s = adj[rs + j];
      sbuf[ns][j] = s;
      ex = __expf(lrelu(es[s] + edn));
    }
    float d = ex;
#pragma unroll
    for (int off = 1; off <= 16; off <<= 1) d += __shfl_xor(d, off);
    float inv = 1.0f / (d + sv);
    if (j < deg) wsh[ns][j] = ex * inv;
    if (j == 0) { sbuf[ns][deg] = n; wsh[ns][deg] = sv * inv; }
    __builtin_amdgcn_wave_barrier();
    for (int e0 = eg2; e0 <= deg; e0 += 16) {
#pragma unroll
      for (int i = 0; i < 4; ++i) {
        int e = e0 + i * 4;
        if (e <= deg) {
          acc += wsh[ns][e] * *(const f4*)&h[sbuf[ns][e] * 32 + 4 * q];
        }
      }
    }
  } else {
    float d = 0.0f;
    for (int jj = rs + j; jj < re; jj += 32) d += __expf(lrelu(es[adj[jj]] + edn));
#pragma unroll
    for (int off = 1; off <= 16; off <<= 1) d += __shfl_xor(d, off);
    float inv = 1.0f / (d + sv);
    for (int base = rs; base < re; base += 32) {
      int cnt = min(32, re - base);
      if (j < cnt) {
        int s = adj[base + j];
        sbuf[ns][j] = s;
        wsh[ns][j] = __expf(lrelu(es[s] + edn)) * inv;
      }
      __builtin_amdgcn_wave_barrier();
      for (int e = eg2; e < cnt; e += 4) {
        acc += wsh[ns][e] * *(const f4*)&h[sbuf[ns][e] * 32 + 4 * q];
      }
      __builtin_amdgcn_wave_barrier();
    }
    if (eg2 == 0) acc += sv * inv * *(const f4*)&h[n * 32 + 4 * q];
  }

#pragma unroll
  for (int off = 8; off <= 16; off <<= 1)
#pragma unroll
    for (int cc = 0; cc < 4; ++cc) acc[cc] += __shfl_xor(acc[cc], off);
  if (eg2 == 0) {
    f4 o = acc + *(const f4*)&b2[4 * q];
#pragma unroll
    for (int cc = 0; cc < 4; ++cc) o[cc] = elu1(o[cc]);
    f4 wc = *(const f4*)&Wc[4 * q];
    float zz = o.x * wc.x + o.y * wc.y + o.z * wc.z + o.w * wc.w;
#pragma unroll
    for (int off = 1; off <= 4; off <<= 1) zz += __shfl_xor(zz, off);
    if (q == 0) z[n] = zz;
  }
}

// ---------------- pooling: one block per graph, sums scalar z ----------------
__global__ __launch_bounds__(256) void k_poolz(const float* __restrict__ z, const int* __restrict__ batch,
                                               const float* __restrict__ bc, float* __restrict__ out) {
  int g = blockIdx.x;
  int lo = 0, hi = NT;
  while (lo < hi) { int mid = (lo + hi) >> 1; if (batch[mid] < g) lo = mid + 1; else hi = mid; }
  int start = lo;
  hi = NT;
  while (lo < hi) { int mid = (lo + hi) >> 1; if (batch[mid] < g + 1) lo = mid + 1; else hi = mid; }
  int end = lo;

  int t = threadIdx.x;
  float s = 0.0f;
  for (int n = start + t; n < end; n += 256) s += z[n];
#pragma unroll
  for (int off = 1; off <= 32; off <<= 1) s += __shfl_xor(s, off);
  __shared__ float sh[4];
  if ((t & 63) == 0) sh[t >> 6] = s;
  __syncthreads();
  if (t == 0) {
    float tot = sh[0] + sh[1] + sh[2] + sh[3];
    float cnt = (float)(end - start);
    out[g] = tot / fmaxf(cnt, 1.0f) + bc[0];
  }
}

extern "C" void kernel_launch(void* const* d_in, const int* in_sizes, int n_in,
                              void* d_out, int out_size, void* d_ws, size_t ws_size,
                              hipStream_t stream) {
  const float* x = (const float*)d_in[0];
  const int* ei = (const int*)d_in[1];
  const int* src = ei;
  const int* dst = ei + ET;
  const int* batch = (const int*)d_in[2];
  const float* W1 = (const float*)d_in[3];
  const float* asrc1 = (const float*)d_in[4];
  const float* adst1 = (const float*)d_in[5];
  const float* b1 = (const float*)d_in[6];
  const float* W2 = (const float*)d_in[7];
  const float* asrc2 = (const float*)d_in[8];
  const float* adst2 = (const float*)d_in[9];
  const float* b2 = (const float*)d_in[10];
  const float* Wc = (const float*)d_in[11];
  const float* bc = (const float*)d_in[12];
  float* out = (float*)d_out;
  char* ws = (char*)d_ws;

  int* row_ptr = (int*)(ws + 0);          // 400004 -> pad 400128
  int* histA = (int*)(ws + 400128);       // 391*256*4 = 400384 -> 800512
  int* btot = (int*)(ws + 800512);        // 1564 -> pad 802112
  int* bbase = (int*)(ws + 802112);       // 1568 -> pad 803712
  float* AB = (float*)(ws + 803712);      // 1024 -> 804736
  int2* ebuf = (int2*)(ws + 804736);      // 12.8MB -> 13604736
  int* adj = (int*)(ws + 13604736);       // 6.4MB -> 20004736
  float* es1 = (float*)(ws + 20004736);   // 1.6MB (16B aligned)
  float* ed1 = (float*)(ws + 21604736);   // 1.6MB
  float* es2 = (float*)(ws + 23204736);   // 400KB
  float* ed2 = (float*)(ws + 23604736);   // 400KB
  float* h2 = (float*)(ws + 24004736);    // 12.8MB -> 36804736
  float* z = (float*)(ws + 36804736);     // 400KB

  // CSR build (bucketed, no global atomics, no memset needed)
  k_histA<<<NBLK_A, 256, 0, stream>>>(dst, histA);
  k_scanB<<<NBK, 256, 0, stream>>>(histA, btot);
  k_scanC<<<1, 512, 0, stream>>>(btot, bbase);
  k_buck<<<NBLK_A, 256, 0, stream>>>(src, dst, histA, bbase, ebuf);
  k_fine<<<NBK, 256, 0, stream>>>(ebuf, bbase, row_ptr, adj);

  // layer 1 attention logits (tiny projection, no h1 materialization)
  k_prep<<<1, 256, 0, stream>>>(W1, asrc1, adst1, AB);
  k_att1<<<(NT + 31) / 32, 256, 0, stream>>>(x, AB, es1, ed1);

  // fused: L1 aggregate (input space) + L1 matvec + ELU + L2 GEMM + L2 logits
  k_agg1f<<<(NT + 7) / 8, 256, 0, stream>>>(row_ptr, adj, es1, ed1, x, W1, b1, W2,
                                            asrc2, adst2, h2, es2, ed2);

  // layer 2 aggregation + ELU + classifier dot (z per node)
  k_agg2<<<(NT + 7) / 8, 256, 0, stream>>>(row_ptr, adj, es2, ed2, h2, b2, Wc, z);

  // pool + bias
  k_poolz<<<GT, 256, 0, stream>>>(z, batch, bc, out);
}